// Round 8
// baseline (401.559 us; speedup 1.0000x reference)
//
#include <hip/hip_runtime.h>

typedef unsigned short ushort_t;
typedef __attribute__((ext_vector_type(8))) __bf16 bf16x8;
typedef __attribute__((ext_vector_type(4))) float floatx4;
typedef __attribute__((ext_vector_type(4))) unsigned short ushortx4;
typedef __attribute__((ext_vector_type(4))) short short4v;
typedef __attribute__((ext_vector_type(2))) unsigned uint2v;

// RNE fp32 -> bf16
__device__ __forceinline__ ushort_t f2bf(float f) {
    union { float f; unsigned u; } v; v.f = f;
    unsigned r = v.u + 0x7fffu + ((v.u >> 16) & 1u);
    return (ushort_t)(r >> 16);
}

// async global->LDS, 16B per lane. LDS dest must be wave-uniform base + lane*16.
__device__ __forceinline__ void gld_lds16(const ushort_t* g, ushort_t* l) {
    __builtin_amdgcn_global_load_lds(
        (const __attribute__((address_space(1))) unsigned*)g,
        (__attribute__((address_space(3))) unsigned*)l, 16, 0, 0);
}

// pack two fp32 -> one dword of 2 bf16 (round via +0x8000, v_perm)
__device__ __forceinline__ unsigned pk_bf16(float a, float b) {
    unsigned ua = __builtin_bit_cast(unsigned, a) + 0x8000u;
    unsigned ub = __builtin_bit_cast(unsigned, b) + 0x8000u;
    return __builtin_amdgcn_perm(ub, ua, 0x07060302u);  // [a.hi16, b.hi16]
}

// ================= prep: fp32->bf16 converts + weight transposes, ONE launch =========
__global__ __launch_bounds__(256) void prep(
    const float* __restrict__ x, const float* __restrict__ y,
    const float* __restrict__ Wq, const float* __restrict__ Wo,
    const float* __restrict__ Wk, const float* __restrict__ Wv,
    ushort_t* __restrict__ xb, ushort_t* __restrict__ yb,
    ushort_t* __restrict__ Wqt, ushort_t* __restrict__ Wot,
    ushort_t* __restrict__ Wkvt) {
    const int bid = blockIdx.x;
    if (bid < 19456) {
        const int NX = 4194304;
        int i = bid * 256 + threadIdx.x;
        float4 v; ushortx4* dst;
        if (i < NX) { v = ((const float4*)x)[i]; dst = (ushortx4*)xb + i; }
        else        { int j = i - NX; v = ((const float4*)y)[j]; dst = (ushortx4*)yb + j; }
        ushortx4 o;
        o.x = f2bf(v.x); o.y = f2bf(v.y); o.z = f2bf(v.z); o.w = f2bf(v.w);
        *dst = o;
        return;
    }
    __shared__ ushort_t t[32][33];
    const float* W; ushort_t* Wt; int K, n0, k0;
    if (bid < 21504) {       // Wq / Wo : [1024,1024]
        int tt = bid - 19456;
        W = (tt >> 10) ? Wo : Wq;
        Wt = (tt >> 10) ? Wot : Wqt;
        K = 1024;
        int r = tt & 1023;
        n0 = (r & 31) * 32; k0 = (r >> 5) * 32;
    } else {                 // Wk / Wv : [768,1024] -> Wkvt rows [0,1024) / [1024,2048)
        int tt = bid - 21504;
        int z = tt / 768, r = tt - z * 768;
        W = z ? Wv : Wk;
        Wt = Wkvt + (size_t)z * 786432;
        K = 768;
        n0 = (r & 31) * 32; k0 = (r >> 5) * 32;
    }
    const int tx = threadIdx.x & 31, ty = threadIdx.x >> 5;
#pragma unroll
    for (int i = 0; i < 4; ++i)
        t[ty + 8 * i][tx] = f2bf(W[(size_t)(k0 + ty + 8 * i) * 1024 + n0 + tx]);
    __syncthreads();
#pragma unroll
    for (int i = 0; i < 4; ++i)
        Wt[(size_t)(n0 + ty + 8 * i) * K + k0 + tx] = t[tx][ty + 8 * i];
}

// ================= 256x128 triple-buffered GEMM core, 2 blocks/CU ====================
// (R5 champion core: 61.5us proj / 770TF / 0 bank conflicts measured)
__device__ __forceinline__ void gemm_tile_core(
    const ushort_t* __restrict__ A, const ushort_t* __restrict__ Bt,
    int K, int NT, ushort_t* lds, floatx4 (&acc)[4][4],
    int m0, int n0, int tid, int wr, int wc, int quad, int l16) {
    const int cx = (quad ^ ((l16 >> 1) & 3)) * 8;

    const int ra = tid >> 2;
    const int ka = (tid & 3) ^ ((tid >> 3) & 3);
    const ushort_t* gA0 = A + (size_t)(m0 + ra) * K + ka * 8;
    const ushort_t* gA1 = gA0 + (size_t)128 * K;
    const ushort_t* gB0 = Bt + (size_t)(n0 + ra) * K + ka * 8;
    const int dA0 = tid * 8, dA1 = tid * 8 + 4096, dB0 = 8192 + tid * 8;

    // prologue: stage tiles 0,1 into buf0,buf1
#pragma unroll
    for (int pt = 0; pt < 2; ++pt) {
        ushort_t* d = lds + pt * 12288;
        gld_lds16(gA0, d + dA0); gld_lds16(gA1, d + dA1); gld_lds16(gB0, d + dB0);
        gA0 += 32; gA1 += 32; gB0 += 32;
    }

    int cur = 0, nxt = 2;
    for (int t = 0; t < NT; ++t) {
        if (t < NT - 1) asm volatile("s_waitcnt vmcnt(3)" ::: "memory");
        else            asm volatile("s_waitcnt vmcnt(0)" ::: "memory");
        __builtin_amdgcn_s_barrier();
        __builtin_amdgcn_sched_barrier(0);
        const ushort_t* Abase = lds + cur * 12288;
        const ushort_t* Bbase = Abase + 8192;
        ushort_t* dn = lds + nxt * 12288;

        bf16x8 af0, af1, af2, af3, bfr[4];
        af0 = *(const bf16x8*)(Abase + (wr * 64 + l16) * 32 + cx);
        af1 = *(const bf16x8*)(Abase + (wr * 64 + 16 + l16) * 32 + cx);
#pragma unroll
        for (int fc = 0; fc < 4; ++fc)
            bfr[fc] = *(const bf16x8*)(Bbase + (wc * 64 + fc * 16 + l16) * 32 + cx);
        __builtin_amdgcn_sched_barrier(0);
        // stage tile t+2 (VMEM only - no lgkm effect)
        if (t + 2 < NT) {
            gld_lds16(gA0, dn + dA0); gld_lds16(gA1, dn + dA1); gld_lds16(gB0, dn + dB0);
            gA0 += 32; gA1 += 32; gB0 += 32;
        }
        __builtin_amdgcn_sched_barrier(0);
        af2 = *(const bf16x8*)(Abase + (wr * 64 + 32 + l16) * 32 + cx);
        af3 = *(const bf16x8*)(Abase + (wr * 64 + 48 + l16) * 32 + cx);
        asm volatile("s_waitcnt lgkmcnt(2)" ::: "memory");   // af0,af1,bfr done
        __builtin_amdgcn_sched_barrier(0);
        __builtin_amdgcn_s_setprio(1);
#pragma unroll
        for (int fc = 0; fc < 4; ++fc) {
            acc[0][fc] = __builtin_amdgcn_mfma_f32_16x16x32_bf16(af0, bfr[fc], acc[0][fc], 0, 0, 0);
            acc[1][fc] = __builtin_amdgcn_mfma_f32_16x16x32_bf16(af1, bfr[fc], acc[1][fc], 0, 0, 0);
        }
        __builtin_amdgcn_s_setprio(0);
        asm volatile("s_waitcnt lgkmcnt(0)" ::: "memory");   // af2,af3 done
        __builtin_amdgcn_sched_barrier(0);
        __builtin_amdgcn_s_setprio(1);
#pragma unroll
        for (int fc = 0; fc < 4; ++fc) {
            acc[2][fc] = __builtin_amdgcn_mfma_f32_16x16x32_bf16(af2, bfr[fc], acc[2][fc], 0, 0, 0);
            acc[3][fc] = __builtin_amdgcn_mfma_f32_16x16x32_bf16(af3, bfr[fc], acc[3][fc], 0, 0, 0);
        }
        __builtin_amdgcn_s_setprio(0);
        __builtin_amdgcn_sched_barrier(0);
        cur = cur == 2 ? 0 : cur + 1;
        nxt = nxt == 2 ? 0 : nxt + 1;
    }
}

// ================= proj: Q + KV projections in ONE launch ============================
__global__ __launch_bounds__(512, 4) void proj256(
    const ushort_t* __restrict__ xb, const ushort_t* __restrict__ yb,
    const ushort_t* __restrict__ Wqt, const ushort_t* __restrict__ Wkvt,
    const float* __restrict__ bq, const float* __restrict__ bk, const float* __restrict__ bv,
    ushort_t* __restrict__ Qc, ushort_t* __restrict__ Kc, ushort_t* __restrict__ Vc,
    float qscale) {
    __shared__ __align__(16) ushort_t lds[36864];
    const int tid = threadIdx.x;
    const int lane = tid & 63, w = tid >> 6;
    const int quad = lane >> 4, l16 = lane & 15;
    const int wr = w >> 1, wc = w & 1;
    const int bid = blockIdx.x;
    floatx4 acc[4][4] = {};

    if (bid < 512) {
        const int swz = (bid & 7) * 64 + (bid >> 3);     // XCD-contiguous m-panels
        const int m0 = (swz >> 3) * 256, n0 = (swz & 7) * 128;
        gemm_tile_core(xb, Wqt, 1024, 32, lds, acc, m0, n0, tid, wr, wc, quad, l16);
#pragma unroll
        for (int i = 0; i < 4; ++i) {
            const int rowb = m0 + wr * 64 + i * 16 + quad * 4;
            const int b_ = rowb >> 12, q = rowb & 4095;
#pragma unroll
            for (int j = 0; j < 4; ++j) {
                const int col = n0 + wc * 64 + j * 16 + l16;
                const float bval = bq[col];
                const int h = col >> 6, d = col & 63;
                ushort_t* base = Qc +
                    (((size_t)b_ * 16 + h) * 32 + (q >> 7)) * 8192 +
                    (d >> 3) * 1024 + (size_t)(q & 127) * 8 + (d & 7);
#pragma unroll
                for (int r = 0; r < 4; ++r)
                    base[r * 8] = f2bf((acc[i][j][r] + bval) * qscale);
            }
        }
    } else {
        const int id2 = bid - 512;                       // 256 blocks: 16m x 16n
        const int swz = (id2 & 7) * 32 + (id2 >> 3);
        const int m0 = (swz >> 4) * 256, n0 = (swz & 15) * 128;
        gemm_tile_core(yb, Wkvt, 768, 24, lds, acc, m0, n0, tid, wr, wc, quad, l16);
        if (n0 < 1024) {   // K -> Kc d-chunked
#pragma unroll
            for (int i = 0; i < 4; ++i) {
                const int rowb = m0 + wr * 64 + i * 16 + quad * 4;
                const int b = rowb >> 10, kvt = (rowb & 1023) >> 6, kvr = rowb & 63;
#pragma unroll
                for (int j = 0; j < 4; ++j) {
                    const int col = n0 + wc * 64 + j * 16 + l16;
                    const int h = col >> 6, d = col & 63;
                    const float bval = bk[col];
                    ushort_t* base = Kc + (((size_t)b * 16 + h) * 16 + kvt) * 4096 +
                                     (d >> 3) * 512 + kvr * 8 + (d & 7);
#pragma unroll
                    for (int r = 0; r < 4; ++r)
                        base[r * 8] = f2bf(acc[i][j][r] + bval);
                }
            }
        } else {           // V -> Vc kv-chunked
#pragma unroll
            for (int i = 0; i < 4; ++i) {
                const int rowb = m0 + wr * 64 + i * 16 + quad * 4;
                const int b = rowb >> 10, kvt = (rowb & 1023) >> 6, sub = (rowb >> 3) & 7;
#pragma unroll
                for (int j = 0; j < 4; ++j) {
                    const int col = n0 + wc * 64 + j * 16 + l16;
                    const int nc = col - 1024;
                    const int h = nc >> 6, d = nc & 63;
                    const float bval = bv[nc];
                    ushortx4 o;
#pragma unroll
                    for (int r = 0; r < 4; ++r) o[r] = f2bf(acc[i][j][r] + bval);
                    *(ushortx4*)(Vc + (((size_t)b * 16 + h) * 16 + kvt) * 4096 +
                                 sub * 512 + d * 8 + (quad & 1) * 4) = o;
                }
            }
        }
    }
}

// ================= O projection: 256x128 tiles -> fp32 + bias ========================
__global__ __launch_bounds__(512, 4) void gemm256_o(
    const ushort_t* __restrict__ A, const ushort_t* __restrict__ Bt,
    const float* __restrict__ bias, float* __restrict__ C) {
    __shared__ __align__(16) ushort_t lds[36864];
    const int tid = threadIdx.x;
    const int lane = tid & 63, w = tid >> 6;
    const int quad = lane >> 4, l16 = lane & 15;
    const int wr = w >> 1, wc = w & 1;
    const int bid = blockIdx.x;
    const int swz = (bid & 7) * 64 + (bid >> 3);
    const int m0 = (swz >> 3) * 256, n0 = (swz & 7) * 128;

    floatx4 acc[4][4] = {};
    gemm_tile_core(A, Bt, 1024, 32, lds, acc, m0, n0, tid, wr, wc, quad, l16);

#pragma unroll
    for (int i = 0; i < 4; ++i) {
        const int rowb = m0 + wr * 64 + i * 16 + quad * 4;
#pragma unroll
        for (int j = 0; j < 4; ++j) {
            const int col = n0 + wc * 64 + j * 16 + l16;
            const float bval = bias[col];
#pragma unroll
            for (int r = 0; r < 4; ++r)
                C[(size_t)(rowb + r) * 1024 + col] = acc[i][j][r] + bval;
        }
    }
}

// ================= flash attention v3: register-resident Q, 32KB LDS dbuf ============
// 5 blocks/CU (LDS 5x32KB = 160KB exactly): tail rounds 2048/1280 = 1.6 vs 2.0.
// K swizzle kept from R7 (measured exactly neutral; both-sides involution).
__device__ __forceinline__ void stage_kv(const ushort_t* kg, const ushort_t* vg,
                                         ushort_t* dst, int tid) {
#pragma unroll
    for (int i = 0; i < 2; ++i) {
        int s = i * 256 + tid;
        int dc = s >> 6, kv = s & 63;
        gld_lds16(kg + dc * 512 + ((kv ^ dc) * 8), dst + s * 8);
        gld_lds16(vg + s * 8, dst + 4096 + s * 8);
    }
}

__global__ __launch_bounds__(256, 5) void attn_kernel(
    const ushort_t* __restrict__ Qc,  // chunked, pre-scaled by 0.125*log2e
    const ushort_t* __restrict__ Kc,  // chunked
    const ushort_t* __restrict__ Vc,  // chunked
    ushort_t* __restrict__ O)         // [4*4096, 1024] bf16 plain
{
    __shared__ __align__(16) ushort_t smem[16384];   // 32 KB: 2 x (K 8KB + V 8KB)
    const int tid = threadIdx.x;
    const int w = tid >> 6, lane = tid & 63;
    const int quad = lane >> 4, l16 = lane & 15;
    const int q0 = blockIdx.x * 128;
    const int bh = blockIdx.y, b = bh >> 4;

    const ushort_t* qg = Qc + ((size_t)bh * 32 + blockIdx.x) * 8192;
    bf16x8 qf[2][2];
#pragma unroll
    for (int ks = 0; ks < 2; ++ks)
#pragma unroll
        for (int qt = 0; qt < 2; ++qt)
            qf[ks][qt] = *(const bf16x8*)(qg +
                ((ks * 4 + quad) * 128 + w * 32 + qt * 16 + l16) * 8);

    const ushort_t* kvbase = Kc + (size_t)bh * 65536;
    const ushort_t* vvbase = Vc + (size_t)bh * 65536;
    stage_kv(kvbase, vvbase, smem, tid);
    __syncthreads();

    floatx4 oacc[4][2] = {};      // [dt][qt] : O^T rows d, col q
    float lsum[2] = {0.f, 0.f};

    for (int kvt = 0; kvt < 16; ++kvt) {
        const int sel = kvt & 1;
        if (kvt < 15)
            stage_kv(kvbase + (kvt + 1) * 4096, vvbase + (kvt + 1) * 4096,
                     smem + (sel ^ 1) * 8192, tid);
        const ushort_t* pK = smem + sel * 8192;
        const ushort_t* pV = pK + 4096;

        // ---- S^T[kv][q] = K Q^T ----  (swizzled K read: LDS[dc][kv^dc])
        floatx4 st[4][2] = {};
#pragma unroll
        for (int ks = 0; ks < 2; ++ks) {
            const int dc = ks * 4 + quad;
            const int l16x = l16 ^ dc;       // (m4*16+l16)^dc = m4*16 + (l16^dc), dc<8
            bf16x8 ak[4];
#pragma unroll
            for (int m4 = 0; m4 < 4; ++m4)
                ak[m4] = *(const bf16x8*)(pK + dc * 512 + (m4 * 16 + l16x) * 8);
#pragma unroll
            for (int m4 = 0; m4 < 4; ++m4)
#pragma unroll
                for (int qt = 0; qt < 2; ++qt)
                    st[m4][qt] = __builtin_amdgcn_mfma_f32_16x16x32_bf16(ak[m4], qf[ks][qt], st[m4][qt], 0, 0, 0);
        }

        // ---- exp2 + pack to bf16 B-frags ----
        uint2v pk[4][2];
#pragma unroll
        for (int qt = 0; qt < 2; ++qt) {
            float acc = 0.f;
#pragma unroll
            for (int m4 = 0; m4 < 4; ++m4) {
                float p0 = __builtin_amdgcn_exp2f(st[m4][qt][0]);
                float p1 = __builtin_amdgcn_exp2f(st[m4][qt][1]);
                float p2 = __builtin_amdgcn_exp2f(st[m4][qt][2]);
                float p3 = __builtin_amdgcn_exp2f(st[m4][qt][3]);
                acc += (p0 + p1) + (p2 + p3);
                pk[m4][qt].x = pk_bf16(p0, p1);
                pk[m4][qt].y = pk_bf16(p2, p3);
            }
            lsum[qt] += acc;
        }

        // ---- O^T += V^T P  (16x16x16, K=16 matches S^T C-layout natively) ----
#pragma unroll
        for (int m4 = 0; m4 < 4; ++m4) {
#pragma unroll
            for (int dt = 0; dt < 4; ++dt) {
                short4v av = *(const short4v*)(pV +
                    ((m4 * 2 + (quad >> 1)) * 64 + dt * 16 + l16) * 8 + (quad & 1) * 4);
#pragma unroll
                for (int qt = 0; qt < 2; ++qt) {
                    short4v bp = __builtin_bit_cast(short4v, pk[m4][qt]);
                    oacc[dt][qt] = __builtin_amdgcn_mfma_f32_16x16x16bf16_1k(av, bp, oacc[dt][qt], 0, 0, 0);
                }
            }
        }
        __syncthreads();
    }

    // ---- epilogue: reduce l across quads, normalize, transpose via LDS ----
    const int h = bh & 15;
    float inv[2];
#pragma unroll
    for (int qt = 0; qt < 2; ++qt) {
        float l = lsum[qt];
        l += __shfl_xor(l, 16, 64);
        l += __shfl_xor(l, 32, 64);
        inv[qt] = 1.0f / l;
    }
#pragma unroll
    for (int dt = 0; dt < 4; ++dt)
#pragma unroll
        for (int qt = 0; qt < 2; ++qt) {
            uint2v o2;
            o2.x = pk_bf16(oacc[dt][qt][0] * inv[qt], oacc[dt][qt][1] * inv[qt]);
            o2.y = pk_bf16(oacc[dt][qt][2] * inv[qt], oacc[dt][qt][3] * inv[qt]);
            *(uint2v*)(smem + (w * 32 + qt * 16 + l16) * 68 + dt * 16 + quad * 4) = o2;
        }
    __syncthreads();
#pragma unroll
    for (int i = 0; i < 8; ++i) {
        int s = i * 256 + tid;
        int row = s >> 4, dc = s & 15;
        ushortx4 v = *(const ushortx4*)(smem + row * 68 + dc * 4);
        *(ushortx4*)(O + (size_t)(b * 4096 + q0 + row) * 1024 + h * 64 + dc * 4) = v;
    }
}

// ---------------- launch ----------------
extern "C" void kernel_launch(void* const* d_in, const int* in_sizes, int n_in,
                              void* d_out, int out_size, void* d_ws, size_t ws_size,
                              hipStream_t stream) {
    const float* x  = (const float*)d_in[0];
    const float* y  = (const float*)d_in[1];
    const float* Wq = (const float*)d_in[2];
    const float* bq = (const float*)d_in[3];
    const float* Wk = (const float*)d_in[4];
    const float* bk = (const float*)d_in[5];
    const float* Wv = (const float*)d_in[6];
    const float* bv = (const float*)d_in[7];
    const float* Wo = (const float*)d_in[8];
    const float* bo = (const float*)d_in[9];

    // workspace 93 MB (was 131): xb aliases Ab (xb dead after proj256; Ab written
    // only by attn, which is stream-ordered after proj256 — alias validated in R6).
    char* ws = (char*)d_ws;
    ushort_t* xbAb = (ushort_t*)(ws);                 // 33,554,432 B  xb -> attn out
    ushort_t* yb   = (ushort_t*)(ws + 33554432);      //  6,291,456
    ushort_t* Wqt  = (ushort_t*)(ws + 39845888);      //  2,097,152
    ushort_t* Wkvt = (ushort_t*)(ws + 41943040);      //  3,145,728  [2048,768]
    ushort_t* Wot  = (ushort_t*)(ws + 45088768);      //  2,097,152
    ushort_t* Qc   = (ushort_t*)(ws + 47185920);      // 33,554,432  chunked
    ushort_t* Kc   = (ushort_t*)(ws + 80740352);      //  8,388,608  chunked
    ushort_t* Vc   = (ushort_t*)(ws + 89128960);      //  8,388,608  chunked  (end 97,517,568)

    const float QSCALE = 0.125f * 1.44269504f;   // softmax scale * log2(e), folded into Q

    prep<<<23040, 256, 0, stream>>>(x, y, Wq, Wo, Wk, Wv, xbAb, yb, Wqt, Wot, Wkvt);
    proj256<<<768, 512, 0, stream>>>(xbAb, yb, Wqt, Wkvt, bq, bk, bv, Qc, Kc, Vc, QSCALE);
    attn_kernel<<<dim3(32, 64), 256, 0, stream>>>(Qc, Kc, Vc, xbAb);
    gemm256_o<<<512, 512, 0, stream>>>(xbAb, Wot, bo, (float*)d_out);
}

// Round 9
// 330.479 us; speedup vs baseline: 1.2151x; 1.2151x over previous
//
#include <hip/hip_runtime.h>

typedef unsigned short ushort_t;
typedef __attribute__((ext_vector_type(8))) __bf16 bf16x8;
typedef __attribute__((ext_vector_type(4))) float floatx4;
typedef __attribute__((ext_vector_type(4))) unsigned short ushortx4;
typedef __attribute__((ext_vector_type(4))) short short4v;
typedef __attribute__((ext_vector_type(2))) unsigned uint2v;

// RNE fp32 -> bf16
__device__ __forceinline__ ushort_t f2bf(float f) {
    union { float f; unsigned u; } v; v.f = f;
    unsigned r = v.u + 0x7fffu + ((v.u >> 16) & 1u);
    return (ushort_t)(r >> 16);
}

// async global->LDS, 16B per lane. LDS dest must be wave-uniform base + lane*16.
__device__ __forceinline__ void gld_lds16(const ushort_t* g, ushort_t* l) {
    __builtin_amdgcn_global_load_lds(
        (const __attribute__((address_space(1))) unsigned*)g,
        (__attribute__((address_space(3))) unsigned*)l, 16, 0, 0);
}

// pack two fp32 -> one dword of 2 bf16 (round via +0x8000, v_perm)
__device__ __forceinline__ unsigned pk_bf16(float a, float b) {
    unsigned ua = __builtin_bit_cast(unsigned, a) + 0x8000u;
    unsigned ub = __builtin_bit_cast(unsigned, b) + 0x8000u;
    return __builtin_amdgcn_perm(ub, ua, 0x07060302u);  // [a.hi16, b.hi16]
}

// ================= prep: fp32->bf16 converts + weight transposes, ONE launch =========
__global__ __launch_bounds__(256) void prep(
    const float* __restrict__ x, const float* __restrict__ y,
    const float* __restrict__ Wq, const float* __restrict__ Wo,
    const float* __restrict__ Wk, const float* __restrict__ Wv,
    ushort_t* __restrict__ xb, ushort_t* __restrict__ yb,
    ushort_t* __restrict__ Wqt, ushort_t* __restrict__ Wot,
    ushort_t* __restrict__ Wkvt) {
    const int bid = blockIdx.x;
    if (bid < 19456) {
        const int NX = 4194304;
        int i = bid * 256 + threadIdx.x;
        float4 v; ushortx4* dst;
        if (i < NX) { v = ((const float4*)x)[i]; dst = (ushortx4*)xb + i; }
        else        { int j = i - NX; v = ((const float4*)y)[j]; dst = (ushortx4*)yb + j; }
        ushortx4 o;
        o.x = f2bf(v.x); o.y = f2bf(v.y); o.z = f2bf(v.z); o.w = f2bf(v.w);
        *dst = o;
        return;
    }
    __shared__ ushort_t t[32][33];
    const float* W; ushort_t* Wt; int K, n0, k0;
    if (bid < 21504) {       // Wq / Wo : [1024,1024]
        int tt = bid - 19456;
        W = (tt >> 10) ? Wo : Wq;
        Wt = (tt >> 10) ? Wot : Wqt;
        K = 1024;
        int r = tt & 1023;
        n0 = (r & 31) * 32; k0 = (r >> 5) * 32;
    } else {                 // Wk / Wv : [768,1024] -> Wkvt rows [0,1024) / [1024,2048)
        int tt = bid - 21504;
        int z = tt / 768, r = tt - z * 768;
        W = z ? Wv : Wk;
        Wt = Wkvt + (size_t)z * 786432;
        K = 768;
        n0 = (r & 31) * 32; k0 = (r >> 5) * 32;
    }
    const int tx = threadIdx.x & 31, ty = threadIdx.x >> 5;
#pragma unroll
    for (int i = 0; i < 4; ++i)
        t[ty + 8 * i][tx] = f2bf(W[(size_t)(k0 + ty + 8 * i) * 1024 + n0 + tx]);
    __syncthreads();
#pragma unroll
    for (int i = 0; i < 4; ++i)
        Wt[(size_t)(n0 + ty + 8 * i) * K + k0 + tx] = t[tx][ty + 8 * i];
}

// ================= 256x128 triple-buffered GEMM core, 2 blocks/CU ====================
// (R5 champion core: 61.5us proj / 770TF / 0 bank conflicts measured)
__device__ __forceinline__ void gemm_tile_core(
    const ushort_t* __restrict__ A, const ushort_t* __restrict__ Bt,
    int K, int NT, ushort_t* lds, floatx4 (&acc)[4][4],
    int m0, int n0, int tid, int wr, int wc, int quad, int l16) {
    const int cx = (quad ^ ((l16 >> 1) & 3)) * 8;

    const int ra = tid >> 2;
    const int ka = (tid & 3) ^ ((tid >> 3) & 3);
    const ushort_t* gA0 = A + (size_t)(m0 + ra) * K + ka * 8;
    const ushort_t* gA1 = gA0 + (size_t)128 * K;
    const ushort_t* gB0 = Bt + (size_t)(n0 + ra) * K + ka * 8;
    const int dA0 = tid * 8, dA1 = tid * 8 + 4096, dB0 = 8192 + tid * 8;

    // prologue: stage tiles 0,1 into buf0,buf1
#pragma unroll
    for (int pt = 0; pt < 2; ++pt) {
        ushort_t* d = lds + pt * 12288;
        gld_lds16(gA0, d + dA0); gld_lds16(gA1, d + dA1); gld_lds16(gB0, d + dB0);
        gA0 += 32; gA1 += 32; gB0 += 32;
    }

    int cur = 0, nxt = 2;
    for (int t = 0; t < NT; ++t) {
        if (t < NT - 1) asm volatile("s_waitcnt vmcnt(3)" ::: "memory");
        else            asm volatile("s_waitcnt vmcnt(0)" ::: "memory");
        __builtin_amdgcn_s_barrier();
        __builtin_amdgcn_sched_barrier(0);
        const ushort_t* Abase = lds + cur * 12288;
        const ushort_t* Bbase = Abase + 8192;
        ushort_t* dn = lds + nxt * 12288;

        bf16x8 af0, af1, af2, af3, bfr[4];
        af0 = *(const bf16x8*)(Abase + (wr * 64 + l16) * 32 + cx);
        af1 = *(const bf16x8*)(Abase + (wr * 64 + 16 + l16) * 32 + cx);
#pragma unroll
        for (int fc = 0; fc < 4; ++fc)
            bfr[fc] = *(const bf16x8*)(Bbase + (wc * 64 + fc * 16 + l16) * 32 + cx);
        __builtin_amdgcn_sched_barrier(0);
        // stage tile t+2 (VMEM only - no lgkm effect)
        if (t + 2 < NT) {
            gld_lds16(gA0, dn + dA0); gld_lds16(gA1, dn + dA1); gld_lds16(gB0, dn + dB0);
            gA0 += 32; gA1 += 32; gB0 += 32;
        }
        __builtin_amdgcn_sched_barrier(0);
        af2 = *(const bf16x8*)(Abase + (wr * 64 + 32 + l16) * 32 + cx);
        af3 = *(const bf16x8*)(Abase + (wr * 64 + 48 + l16) * 32 + cx);
        asm volatile("s_waitcnt lgkmcnt(2)" ::: "memory");   // af0,af1,bfr done
        __builtin_amdgcn_sched_barrier(0);
        __builtin_amdgcn_s_setprio(1);
#pragma unroll
        for (int fc = 0; fc < 4; ++fc) {
            acc[0][fc] = __builtin_amdgcn_mfma_f32_16x16x32_bf16(af0, bfr[fc], acc[0][fc], 0, 0, 0);
            acc[1][fc] = __builtin_amdgcn_mfma_f32_16x16x32_bf16(af1, bfr[fc], acc[1][fc], 0, 0, 0);
        }
        __builtin_amdgcn_s_setprio(0);
        asm volatile("s_waitcnt lgkmcnt(0)" ::: "memory");   // af2,af3 done
        __builtin_amdgcn_sched_barrier(0);
        __builtin_amdgcn_s_setprio(1);
#pragma unroll
        for (int fc = 0; fc < 4; ++fc) {
            acc[2][fc] = __builtin_amdgcn_mfma_f32_16x16x32_bf16(af2, bfr[fc], acc[2][fc], 0, 0, 0);
            acc[3][fc] = __builtin_amdgcn_mfma_f32_16x16x32_bf16(af3, bfr[fc], acc[3][fc], 0, 0, 0);
        }
        __builtin_amdgcn_s_setprio(0);
        __builtin_amdgcn_sched_barrier(0);
        cur = cur == 2 ? 0 : cur + 1;
        nxt = nxt == 2 ? 0 : nxt + 1;
    }
}

// ================= proj: Q + KV projections in ONE launch ============================
__global__ __launch_bounds__(512, 4) void proj256(
    const ushort_t* __restrict__ xb, const ushort_t* __restrict__ yb,
    const ushort_t* __restrict__ Wqt, const ushort_t* __restrict__ Wkvt,
    const float* __restrict__ bq, const float* __restrict__ bk, const float* __restrict__ bv,
    ushort_t* __restrict__ Qc, ushort_t* __restrict__ Kc, ushort_t* __restrict__ Vc,
    float qscale) {
    __shared__ __align__(16) ushort_t lds[36864];
    const int tid = threadIdx.x;
    const int lane = tid & 63, w = tid >> 6;
    const int quad = lane >> 4, l16 = lane & 15;
    const int wr = w >> 1, wc = w & 1;
    const int bid = blockIdx.x;
    floatx4 acc[4][4] = {};

    if (bid < 512) {
        const int swz = (bid & 7) * 64 + (bid >> 3);     // XCD-contiguous m-panels
        const int m0 = (swz >> 3) * 256, n0 = (swz & 7) * 128;
        gemm_tile_core(xb, Wqt, 1024, 32, lds, acc, m0, n0, tid, wr, wc, quad, l16);
#pragma unroll
        for (int i = 0; i < 4; ++i) {
            const int rowb = m0 + wr * 64 + i * 16 + quad * 4;
            const int b_ = rowb >> 12, q = rowb & 4095;
#pragma unroll
            for (int j = 0; j < 4; ++j) {
                const int col = n0 + wc * 64 + j * 16 + l16;
                const float bval = bq[col];
                const int h = col >> 6, d = col & 63;
                ushort_t* base = Qc +
                    (((size_t)b_ * 16 + h) * 32 + (q >> 7)) * 8192 +
                    (d >> 3) * 1024 + (size_t)(q & 127) * 8 + (d & 7);
#pragma unroll
                for (int r = 0; r < 4; ++r)
                    base[r * 8] = f2bf((acc[i][j][r] + bval) * qscale);
            }
        }
    } else {
        const int id2 = bid - 512;                       // 256 blocks: 16m x 16n
        const int swz = (id2 & 7) * 32 + (id2 >> 3);
        const int m0 = (swz >> 4) * 256, n0 = (swz & 15) * 128;
        gemm_tile_core(yb, Wkvt, 768, 24, lds, acc, m0, n0, tid, wr, wc, quad, l16);
        if (n0 < 1024) {   // K -> Kc d-chunked
#pragma unroll
            for (int i = 0; i < 4; ++i) {
                const int rowb = m0 + wr * 64 + i * 16 + quad * 4;
                const int b = rowb >> 10, kvt = (rowb & 1023) >> 6, kvr = rowb & 63;
#pragma unroll
                for (int j = 0; j < 4; ++j) {
                    const int col = n0 + wc * 64 + j * 16 + l16;
                    const int h = col >> 6, d = col & 63;
                    const float bval = bk[col];
                    ushort_t* base = Kc + (((size_t)b * 16 + h) * 16 + kvt) * 4096 +
                                     (d >> 3) * 512 + kvr * 8 + (d & 7);
#pragma unroll
                    for (int r = 0; r < 4; ++r)
                        base[r * 8] = f2bf(acc[i][j][r] + bval);
                }
            }
        } else {           // V -> Vc kv-chunked
#pragma unroll
            for (int i = 0; i < 4; ++i) {
                const int rowb = m0 + wr * 64 + i * 16 + quad * 4;
                const int b = rowb >> 10, kvt = (rowb & 1023) >> 6, sub = (rowb >> 3) & 7;
#pragma unroll
                for (int j = 0; j < 4; ++j) {
                    const int col = n0 + wc * 64 + j * 16 + l16;
                    const int nc = col - 1024;
                    const int h = nc >> 6, d = nc & 63;
                    const float bval = bv[nc];
                    ushortx4 o;
#pragma unroll
                    for (int r = 0; r < 4; ++r) o[r] = f2bf(acc[i][j][r] + bval);
                    *(ushortx4*)(Vc + (((size_t)b * 16 + h) * 16 + kvt) * 4096 +
                                 sub * 512 + d * 8 + (quad & 1) * 4) = o;
                }
            }
        }
    }
}

// ================= O projection: 256x128 tiles -> fp32 + bias ========================
__global__ __launch_bounds__(512, 4) void gemm256_o(
    const ushort_t* __restrict__ A, const ushort_t* __restrict__ Bt,
    const float* __restrict__ bias, float* __restrict__ C) {
    __shared__ __align__(16) ushort_t lds[36864];
    const int tid = threadIdx.x;
    const int lane = tid & 63, w = tid >> 6;
    const int quad = lane >> 4, l16 = lane & 15;
    const int wr = w >> 1, wc = w & 1;
    const int bid = blockIdx.x;
    const int swz = (bid & 7) * 64 + (bid >> 3);
    const int m0 = (swz >> 3) * 256, n0 = (swz & 7) * 128;

    floatx4 acc[4][4] = {};
    gemm_tile_core(A, Bt, 1024, 32, lds, acc, m0, n0, tid, wr, wc, quad, l16);

#pragma unroll
    for (int i = 0; i < 4; ++i) {
        const int rowb = m0 + wr * 64 + i * 16 + quad * 4;
#pragma unroll
        for (int j = 0; j < 4; ++j) {
            const int col = n0 + wc * 64 + j * 16 + l16;
            const float bval = bias[col];
#pragma unroll
            for (int r = 0; r < 4; ++r)
                C[(size_t)(rowb + r) * 1024 + col] = acc[i][j][r] + bval;
        }
    }
}

// ================= flash attention: counted-vmcnt KV double-buffer [R9] ==============
// Back to 4 blocks/CU (R8's 5/CU blew the per-XCD L2 working set: 40 bh x 128KB =
// 5MB > 4MB -> FETCH 82->222MB, attn 95->164us. At 4/CU it is exactly 4.0MB.)
// R9 change: replace per-tile __syncthreads (compiler drains vmcnt(0) -> prefetch
// must land before barrier, the m97 stall) with the R5-proven counted-gate pattern:
// issue stage(t+1), vmcnt(4) (tile t's 4 per-thread loads forced landed, t+1's 4
// stay in flight), raw s_barrier, compute, raw s_barrier. Drain only at t=15.
__device__ __forceinline__ void stage_kv(const ushort_t* kg, const ushort_t* vg,
                                         ushort_t* dst, int tid) {
#pragma unroll
    for (int i = 0; i < 2; ++i) {
        int s = i * 256 + tid;
        int dc = s >> 6, kv = s & 63;
        gld_lds16(kg + dc * 512 + ((kv ^ dc) * 8), dst + s * 8);
        gld_lds16(vg + s * 8, dst + 4096 + s * 8);
    }
}

__global__ __launch_bounds__(256, 4) void attn_kernel(
    const ushort_t* __restrict__ Qc,  // chunked, pre-scaled by 0.125*log2e
    const ushort_t* __restrict__ Kc,  // chunked
    const ushort_t* __restrict__ Vc,  // chunked
    ushort_t* __restrict__ O)         // [4*4096, 1024] bf16 plain
{
    __shared__ __align__(16) ushort_t smem[16384];   // 32 KB: 2 x (K 8KB + V 8KB)
    const int tid = threadIdx.x;
    const int w = tid >> 6, lane = tid & 63;
    const int quad = lane >> 4, l16 = lane & 15;
    const int q0 = blockIdx.x * 128;
    const int bh = blockIdx.y, b = bh >> 4;

    const ushort_t* qg = Qc + ((size_t)bh * 32 + blockIdx.x) * 8192;
    bf16x8 qf[2][2];
#pragma unroll
    for (int ks = 0; ks < 2; ++ks)
#pragma unroll
        for (int qt = 0; qt < 2; ++qt)
            qf[ks][qt] = *(const bf16x8*)(qg +
                ((ks * 4 + quad) * 128 + w * 32 + qt * 16 + l16) * 8);

    const ushort_t* kvbase = Kc + (size_t)bh * 65536;
    const ushort_t* vvbase = Vc + (size_t)bh * 65536;
    stage_kv(kvbase, vvbase, smem, tid);      // tile 0: 4 loads/thread in flight

    floatx4 oacc[4][2] = {};      // [dt][qt] : O^T rows d, col q
    float lsum[2] = {0.f, 0.f};

    for (int kvt = 0; kvt < 16; ++kvt) {
        const int sel = kvt & 1;
        if (kvt < 15) {
            stage_kv(kvbase + (kvt + 1) * 4096, vvbase + (kvt + 1) * 4096,
                     smem + (sel ^ 1) * 8192, tid);
            asm volatile("s_waitcnt vmcnt(4)" ::: "memory");   // tile kvt landed
        } else {
            asm volatile("s_waitcnt vmcnt(0)" ::: "memory");
        }
        __builtin_amdgcn_s_barrier();          // all waves: buf[sel] ready
        __builtin_amdgcn_sched_barrier(0);
        const ushort_t* pK = smem + sel * 8192;
        const ushort_t* pV = pK + 4096;

        // ---- S^T[kv][q] = K Q^T ----  (swizzled K read: LDS[dc][kv^dc])
        floatx4 st[4][2] = {};
#pragma unroll
        for (int ks = 0; ks < 2; ++ks) {
            const int dc = ks * 4 + quad;
            const int l16x = l16 ^ dc;       // (m4*16+l16)^dc = m4*16 + (l16^dc), dc<8
            bf16x8 ak[4];
#pragma unroll
            for (int m4 = 0; m4 < 4; ++m4)
                ak[m4] = *(const bf16x8*)(pK + dc * 512 + (m4 * 16 + l16x) * 8);
#pragma unroll
            for (int m4 = 0; m4 < 4; ++m4)
#pragma unroll
                for (int qt = 0; qt < 2; ++qt)
                    st[m4][qt] = __builtin_amdgcn_mfma_f32_16x16x32_bf16(ak[m4], qf[ks][qt], st[m4][qt], 0, 0, 0);
        }

        // ---- exp2 + pack to bf16 B-frags ----
        uint2v pk[4][2];
#pragma unroll
        for (int qt = 0; qt < 2; ++qt) {
            float acc = 0.f;
#pragma unroll
            for (int m4 = 0; m4 < 4; ++m4) {
                float p0 = __builtin_amdgcn_exp2f(st[m4][qt][0]);
                float p1 = __builtin_amdgcn_exp2f(st[m4][qt][1]);
                float p2 = __builtin_amdgcn_exp2f(st[m4][qt][2]);
                float p3 = __builtin_amdgcn_exp2f(st[m4][qt][3]);
                acc += (p0 + p1) + (p2 + p3);
                pk[m4][qt].x = pk_bf16(p0, p1);
                pk[m4][qt].y = pk_bf16(p2, p3);
            }
            lsum[qt] += acc;
        }

        // ---- O^T += V^T P  (16x16x16, K=16 matches S^T C-layout natively) ----
#pragma unroll
        for (int m4 = 0; m4 < 4; ++m4) {
#pragma unroll
            for (int dt = 0; dt < 4; ++dt) {
                short4v av = *(const short4v*)(pV +
                    ((m4 * 2 + (quad >> 1)) * 64 + dt * 16 + l16) * 8 + (quad & 1) * 4);
#pragma unroll
                for (int qt = 0; qt < 2; ++qt) {
                    short4v bp = __builtin_bit_cast(short4v, pk[m4][qt]);
                    oacc[dt][qt] = __builtin_amdgcn_mfma_f32_16x16x16bf16_1k(av, bp, oacc[dt][qt], 0, 0, 0);
                }
            }
        }
        __builtin_amdgcn_s_barrier();          // reads of buf[sel] done (next iter overwrites)
        __builtin_amdgcn_sched_barrier(0);
    }

    // ---- epilogue: reduce l across quads, normalize, transpose via LDS ----
    const int h = bh & 15;
    float inv[2];
#pragma unroll
    for (int qt = 0; qt < 2; ++qt) {
        float l = lsum[qt];
        l += __shfl_xor(l, 16, 64);
        l += __shfl_xor(l, 32, 64);
        inv[qt] = 1.0f / l;
    }
#pragma unroll
    for (int dt = 0; dt < 4; ++dt)
#pragma unroll
        for (int qt = 0; qt < 2; ++qt) {
            uint2v o2;
            o2.x = pk_bf16(oacc[dt][qt][0] * inv[qt], oacc[dt][qt][1] * inv[qt]);
            o2.y = pk_bf16(oacc[dt][qt][2] * inv[qt], oacc[dt][qt][3] * inv[qt]);
            *(uint2v*)(smem + (w * 32 + qt * 16 + l16) * 68 + dt * 16 + quad * 4) = o2;
        }
    __syncthreads();
#pragma unroll
    for (int i = 0; i < 8; ++i) {
        int s = i * 256 + tid;
        int row = s >> 4, dc = s & 15;
        ushortx4 v = *(const ushortx4*)(smem + row * 68 + dc * 4);
        *(ushortx4*)(O + (size_t)(b * 4096 + q0 + row) * 1024 + h * 64 + dc * 4) = v;
    }
}

// ---------------- launch ----------------
extern "C" void kernel_launch(void* const* d_in, const int* in_sizes, int n_in,
                              void* d_out, int out_size, void* d_ws, size_t ws_size,
                              hipStream_t stream) {
    const float* x  = (const float*)d_in[0];
    const float* y  = (const float*)d_in[1];
    const float* Wq = (const float*)d_in[2];
    const float* bq = (const float*)d_in[3];
    const float* Wk = (const float*)d_in[4];
    const float* bk = (const float*)d_in[5];
    const float* Wv = (const float*)d_in[6];
    const float* bv = (const float*)d_in[7];
    const float* Wo = (const float*)d_in[8];
    const float* bo = (const float*)d_in[9];

    char* ws = (char*)d_ws;
    ushort_t* xb   = (ushort_t*)(ws);                 // 33,554,432 B
    ushort_t* yb   = (ushort_t*)(ws + 33554432);      //  6,291,456
    ushort_t* Wqt  = (ushort_t*)(ws + 39845888);      //  2,097,152
    ushort_t* Wkvt = (ushort_t*)(ws + 41943040);      //  3,145,728  [2048,768]
    ushort_t* Wot  = (ushort_t*)(ws + 45088768);      //  2,097,152
    ushort_t* Qc   = (ushort_t*)(ws + 47185920);      // 33,554,432  chunked
    ushort_t* Kc   = (ushort_t*)(ws + 80740352);      //  8,388,608  chunked
    ushort_t* Vc   = (ushort_t*)(ws + 89128960);      //  8,388,608  chunked
    ushort_t* Ab   = (ushort_t*)(ws + 97517568);      // 33,554,432  plain

    const float QSCALE = 0.125f * 1.44269504f;   // softmax scale * log2(e), folded into Q

    prep<<<23040, 256, 0, stream>>>(x, y, Wq, Wo, Wk, Wv, xb, yb, Wqt, Wot, Wkvt);
    proj256<<<768, 512, 0, stream>>>(xb, yb, Wqt, Wkvt, bq, bk, bv, Qc, Kc, Vc, QSCALE);
    attn_kernel<<<dim3(32, 64), 256, 0, stream>>>(Qc, Kc, Vc, Ab);
    gemm256_o<<<512, 512, 0, stream>>>(Ab, Wot, bo, (float*)d_out);
}